// Round 1
// baseline (659.403 us; speedup 1.0000x reference)
//
#include <hip/hip_runtime.h>

// Autoregressive FFNN: out[b,0]=0; for t=1..511:
//   mi = [x[b,t,0:63], pred_prev]  (64)
//   h  = relu(mi @ W1 + b1)        (1024)
//   pred = h @ W2 + b2             (1)
// B=4096, T=512, F=63. One persistent WG per CU, 16 batch rows per WG,
// W1 as bf16 MFMA B-fragments in registers, fp32 accumulate.

#define TT 512
#define FF 63

typedef __attribute__((ext_vector_type(8))) short short8;
typedef __attribute__((ext_vector_type(4))) float f32x4;

__device__ __forceinline__ unsigned short f2bf(float f) {
  union { float f; unsigned u; } v;
  v.f = f;
  unsigned r = v.u + 0x7FFFu + ((v.u >> 16) & 1u);  // RNE
  return (unsigned short)(r >> 16);
}

__global__ __launch_bounds__(512, 2)
void ffnn_ar_kernel(const float* __restrict__ x,
                    const float* __restrict__ W1,
                    const float* __restrict__ b1,
                    const float* __restrict__ W2,
                    const float* __restrict__ b2p,
                    float* __restrict__ out) {
  // A-staging: 16 rows x 64 (63 x + 1 pred), bf16, padded stride 72 for banks
  __shared__ __align__(16) unsigned short lds_A[16][72];
  __shared__ float lds_part[8][16];

  const int tid  = threadIdx.x;
  const int lane = tid & 63;
  const int w    = tid >> 6;        // wave 0..7
  const int col  = lane & 15;       // A-row / C-col / B-col within tile
  const int grp  = lane >> 4;       // 0..3 k-group
  const int br   = blockIdx.x * 16; // batch row base

  // ---- one-time: W1 B-fragments (bf16), b1, W2 per-lane ----
  // B-frag layout: lane holds B[k = ks*32 + grp*8 + j][n], j=0..7
  short8 bfr[8][2];
  float  b1f[8], w2f[8];
#pragma unroll
  for (int i = 0; i < 8; ++i) {
    const int n = (w * 8 + i) * 16 + col;  // global hidden column
#pragma unroll
    for (int ks = 0; ks < 2; ++ks) {
      short8 f;
#pragma unroll
      for (int j = 0; j < 8; ++j) {
        const int k = ks * 32 + grp * 8 + j;
        f[j] = (short)f2bf(W1[k * 1024 + n]);
      }
      bfr[i][ks] = f;
    }
    b1f[i] = b1[n];
    w2f[i] = W2[n];
  }
  const float b2 = b2p[0];

  // ---- x staging assignment: 16 groups of 32 threads, one row each ----
  const int srow = tid >> 5;   // 0..15
  const int sl   = tid & 31;   // 0..31
  const long rowbase = (long)(br + srow) * TT * FF;

  // prologue: prefetch x[:,1,:], init pred slot + out[:,0]
  float xa = x[rowbase + 1 * FF + sl];
  float xb = (sl < 31) ? x[rowbase + 1 * FF + 32 + sl] : 0.0f;
  if (tid < 16) {
    lds_A[tid][63] = 0;  // bf16(0.0) == 0
    out[(long)(br + tid) * TT + 0] = 0.0f;
  }

  for (int t = 1; t < TT; ++t) {
    // stage x_t (from prefetch regs) into lds_A as bf16
    lds_A[srow][sl] = f2bf(xa);
    if (sl < 31) lds_A[srow][32 + sl] = f2bf(xb);

    // prefetch t+1 (clamped; last-iter values unused)
    {
      const int tp = (t + 1 < TT) ? (t + 1) : (TT - 1);
      xa = x[rowbase + (long)tp * FF + sl];
      if (sl < 31) xb = x[rowbase + (long)tp * FF + 32 + sl];
    }

    __syncthreads();  // barrier A: staging done

    // A-fragments: lane holds A[col][grp*8 + j] (k 0..31) and +32 (k 32..63)
    const short8 a0 = *reinterpret_cast<const short8*>(&lds_A[col][grp * 8]);
    const short8 a1 = *reinterpret_cast<const short8*>(&lds_A[col][32 + grp * 8]);

    // layer 1: 8 N-tiles x (K=64) per wave
    f32x4 acc[8];
#pragma unroll
    for (int i = 0; i < 8; ++i) {
      f32x4 c = {0.f, 0.f, 0.f, 0.f};
      c = __builtin_amdgcn_mfma_f32_16x16x32_bf16(a0, bfr[i][0], c, 0, 0, 0);
      c = __builtin_amdgcn_mfma_f32_16x16x32_bf16(a1, bfr[i][1], c, 0, 0, 0);
      acc[i] = c;
    }

    // layer 2 partial: h = relu(z + b1), part += h * w2  (4 rows per lane)
    f32x4 part = {0.f, 0.f, 0.f, 0.f};
#pragma unroll
    for (int i = 0; i < 8; ++i) {
#pragma unroll
      for (int q = 0; q < 4; ++q) {
        const float h = fmaxf(acc[i][q] + b1f[i], 0.f);
        part[q] += h * w2f[i];
      }
    }

    // reduce over the 16 lanes of each k-group (different cols, same rows)
#pragma unroll
    for (int m = 1; m < 16; m <<= 1) {
#pragma unroll
      for (int q = 0; q < 4; ++q)
        part[q] += __shfl_xor(part[q], m, 64);
    }
    if (col == 0) {
#pragma unroll
      for (int q = 0; q < 4; ++q)
        lds_part[w][grp * 4 + q] = part[q];  // row = grp*4+q
    }

    __syncthreads();  // barrier B: partials visible

    if (tid < 16) {
      float p = b2;
#pragma unroll
      for (int ww = 0; ww < 8; ++ww) p += lds_part[ww][tid];
      out[(long)(br + tid) * TT + t] = p;
      lds_A[tid][63] = f2bf(p);  // feed back for next step (ordered by barrier A)
    }
  }
}

extern "C" void kernel_launch(void* const* d_in, const int* in_sizes, int n_in,
                              void* d_out, int out_size, void* d_ws, size_t ws_size,
                              hipStream_t stream) {
  const float* x   = (const float*)d_in[0];
  // d_in[1] = labels (unused by reference forward)
  const float* W1  = (const float*)d_in[2];
  const float* b1  = (const float*)d_in[3];
  const float* W2  = (const float*)d_in[4];
  const float* b2  = (const float*)d_in[5];
  float* out = (float*)d_out;

  ffnn_ar_kernel<<<256, 512, 0, stream>>>(x, W1, b1, W2, b2, out);
}

// Round 2
// 543.044 us; speedup vs baseline: 1.2143x; 1.2143x over previous
//
#include <hip/hip_runtime.h>

// Autoregressive FFNN, single-barrier-per-step persistent kernel.
// out[b,0]=0; for t=1..511: mi=[x[b,t,:], pred_prev]; h=relu(mi@W1+b1); pred=h@W2+b2.
// B=4096, T=512, F=63. 256 WGs x 512 thr, 16 batch rows/WG, W1 bf16 B-frags in VGPRs.
// pred feedback enters layer-1 as a VALU term (pred*W1[63,:]) so the MFMA never
// waits on it; lds_A and lds_part are double-buffered -> ONE __syncthreads per step.

#define TT 512
#define FF 63

typedef __attribute__((ext_vector_type(8))) short short8;
typedef __attribute__((ext_vector_type(4))) float f32x4;

__device__ __forceinline__ unsigned short f2bf(float f) {
  union { float f; unsigned u; } v;
  v.f = f;
  unsigned r = v.u + 0x7FFFu + ((v.u >> 16) & 1u);  // RNE
  return (unsigned short)(r >> 16);
}

__global__ __launch_bounds__(512, 2)
void ffnn_ar_kernel(const float* __restrict__ x,
                    const float* __restrict__ W1,
                    const float* __restrict__ b1,
                    const float* __restrict__ W2,
                    const float* __restrict__ b2p,
                    float* __restrict__ out) {
  __shared__ __align__(16) unsigned short lds_A[2][16][72];  // bf16 x-tiles, dbuf
  __shared__ __align__(16) float lds_part[2][16][8];         // [buf][row][wave]

  const int tid  = threadIdx.x;
  const int lane = tid & 63;
  const int w    = tid >> 6;        // wave 0..7
  const int col  = lane & 15;       // C col / A row / B col
  const int grp  = lane >> 4;       // k-group 0..3
  const int br   = blockIdx.x * 16; // batch row base

  // ---- one-time: W1 B-frags (bf16), b1, W2, W1[63,:] per lane ----
  short8 bfr[8][2];
  float  b1f[8], w2f[8], w63f[8];
#pragma unroll
  for (int i = 0; i < 8; ++i) {
    const int n = (w * 8 + i) * 16 + col;
#pragma unroll
    for (int ks = 0; ks < 2; ++ks) {
      short8 f;
#pragma unroll
      for (int j = 0; j < 8; ++j) {
        const int k = ks * 32 + grp * 8 + j;
        f[j] = (short)f2bf(W1[k * 1024 + n]);
      }
      bfr[i][ks] = f;
    }
    b1f[i]  = b1[n];
    w2f[i]  = W2[n];
    w63f[i] = W1[63 * 1024 + n];
  }
  const float b2  = b2p[0];
  const float b2w = (w == 0) ? b2 : 0.f;  // b2 baked into wave0's partial

  // ---- x staging: 16 groups of 32 threads, one row each ----
  const int srow = tid >> 5;   // 0..15
  const int sl   = tid & 31;   // 0..31
  const long rowbase = (long)(br + srow) * TT * FF;

  // prologue: stage x_1 into lds_A[1]; zero k=63 col + part buffer 0; prefetch x_2,x_3
  {
    const float xa1 = x[rowbase + (long)1 * FF + sl];
    const float xb1 = (sl < 31) ? x[rowbase + (long)1 * FF + 32 + sl] : 0.f;
    lds_A[1][srow][sl] = f2bf(xa1);
    if (sl < 31) lds_A[1][srow][32 + sl] = f2bf(xb1);
  }
  if (tid < 16) { lds_A[0][tid][63] = 0; lds_A[1][tid][63] = 0; }
  if (tid < 128) reinterpret_cast<float*>(lds_part)[tid] = 0.f;  // buffer 0

  float xa_s0 = x[rowbase + (long)2 * FF + sl];                              // x_2
  float xb_s0 = (sl < 31) ? x[rowbase + (long)2 * FF + 32 + sl] : 0.f;
  float xa_s1 = x[rowbase + (long)3 * FF + sl];                              // x_3
  float xb_s1 = (sl < 31) ? x[rowbase + (long)3 * FF + 32 + sl] : 0.f;

  __syncthreads();

#define STEP(CUR, T, XA, XB)                                                        \
  {                                                                                  \
    const short8 a0 = *reinterpret_cast<const short8*>(&lds_A[CUR][col][grp * 8]);   \
    const short8 a1 = *reinterpret_cast<const short8*>(&lds_A[CUR][col][32 + grp * 8]); \
    f32x4 acc[8];                                                                    \
    _Pragma("unroll") for (int i = 0; i < 8; ++i) {                                  \
      f32x4 c = {0.f, 0.f, 0.f, 0.f};                                                \
      c = __builtin_amdgcn_mfma_f32_16x16x32_bf16(a0, bfr[i][0], c, 0, 0, 0);        \
      c = __builtin_amdgcn_mfma_f32_16x16x32_bf16(a1, bfr[i][1], c, 0, 0, 0);        \
      acc[i] = c;                                                                    \
    }                                                                                \
    float p = 0.f;                                                                   \
    if (lane < 16) {                                                                 \
      const f32x4 u = *reinterpret_cast<const f32x4*>(&lds_part[(CUR) ^ 1][lane][0]); \
      const f32x4 v = *reinterpret_cast<const f32x4*>(&lds_part[(CUR) ^ 1][lane][4]); \
      p = ((u[0] + u[1]) + (u[2] + u[3])) + ((v[0] + v[1]) + (v[2] + v[3]));         \
      if (w == 0) out[(long)(br + lane) * TT + ((T) - 1)] = p;                       \
    }                                                                                \
    float predq[4];                                                                  \
    _Pragma("unroll") for (int q = 0; q < 4; ++q)                                    \
      predq[q] = __shfl(p, grp * 4 + q, 64);                                         \
    f32x4 part = {0.f, 0.f, 0.f, 0.f};                                               \
    _Pragma("unroll") for (int i = 0; i < 8; ++i) {                                  \
      _Pragma("unroll") for (int q = 0; q < 4; ++q) {                                \
        const float z = fmaf(predq[q], w63f[i], acc[i][q]) + b1f[i];                 \
        part[q] = fmaf(fmaxf(z, 0.f), w2f[i], part[q]);                              \
      }                                                                              \
    }                                                                                \
    _Pragma("unroll") for (int m = 1; m < 16; m <<= 1) {                             \
      _Pragma("unroll") for (int q = 0; q < 4; ++q)                                  \
        part[q] += __shfl_xor(part[q], m, 64);                                       \
    }                                                                                \
    if (col == 0) {                                                                  \
      _Pragma("unroll") for (int q = 0; q < 4; ++q)                                  \
        lds_part[CUR][grp * 4 + q][w] = part[q] + b2w;                               \
    }                                                                                \
    lds_A[(CUR) ^ 1][srow][sl] = f2bf(XA);                                           \
    if (sl < 31) lds_A[(CUR) ^ 1][srow][32 + sl] = f2bf(XB);                         \
    {                                                                                \
      const int tp = ((T) + 3 < TT) ? (T) + 3 : TT - 1;                              \
      XA = x[rowbase + (long)tp * FF + sl];                                          \
      if (sl < 31) XB = x[rowbase + (long)tp * FF + 32 + sl];                        \
    }                                                                                \
    __syncthreads();                                                                 \
  }

#pragma unroll 1
  for (int t = 1; t + 1 < TT; t += 2) {
    STEP(1, t, xa_s0, xb_s0)
    STEP(0, t + 1, xa_s1, xb_s1)
  }
  STEP(1, TT - 1, xa_s0, xb_s0)  // t = 511 (odd)

  // finalize pred_{511} (written to lds_part[1]) -> out[., 511]
  if (lane < 16 && w == 0) {
    const f32x4 u = *reinterpret_cast<const f32x4*>(&lds_part[1][lane][0]);
    const f32x4 v = *reinterpret_cast<const f32x4*>(&lds_part[1][lane][4]);
    const float p = ((u[0] + u[1]) + (u[2] + u[3])) + ((v[0] + v[1]) + (v[2] + v[3]));
    out[(long)(br + lane) * TT + (TT - 1)] = p;
  }
#undef STEP
}

extern "C" void kernel_launch(void* const* d_in, const int* in_sizes, int n_in,
                              void* d_out, int out_size, void* d_ws, size_t ws_size,
                              hipStream_t stream) {
  const float* x   = (const float*)d_in[0];
  // d_in[1] = labels (unused by the reference forward pass)
  const float* W1  = (const float*)d_in[2];
  const float* b1  = (const float*)d_in[3];
  const float* W2  = (const float*)d_in[4];
  const float* b2  = (const float*)d_in[5];
  float* out = (float*)d_out;

  ffnn_ar_kernel<<<256, 512, 0, stream>>>(x, W1, b1, W2, b2, out);
}